// Round 1
// baseline (524.340 us; speedup 1.0000x reference)
//
#include <hip/hip_runtime.h>
#include <stdint.h>

#define N_NODES_C 100000
#define N_EDGES_C 1600000
#define DIM 64
#define BN_EPS_C 1e-5f

// ---------- index helper: supports int32 or int64 edge_index ----------
__device__ __forceinline__ int ld_idx(const void* p, int is64, size_t i) {
    if (is64) return (int)((const long long*)p)[i];
    return ((const int*)p)[i];
}

// Probe: if edge_index is int64, the high 32-bit word of every element is 0
// (values are in [0, 100000)). Check odd words of the first 32 elements.
__global__ void probe_kernel(const unsigned int* __restrict__ p, int* __restrict__ flag) {
    if (threadIdx.x == 0 && blockIdx.x == 0) {
        int is64 = 1;
        for (int i = 1; i < 64; i += 2) {
            if (p[i] != 0u) { is64 = 0; break; }
        }
        *flag = is64;
    }
}

// ---------- degree count (in-degree at tgt) ----------
__global__ __launch_bounds__(256) void deg_kernel(const void* __restrict__ ei,
                                                  const int* __restrict__ flag,
                                                  int* __restrict__ deg) {
    int is64 = *flag;
    int stride = gridDim.x * blockDim.x;
    for (int e = blockIdx.x * blockDim.x + threadIdx.x; e < N_EDGES_C; e += stride) {
        int t = ld_idx(ei, is64, (size_t)N_EDGES_C + e);
        atomicAdd(&deg[t], 1);
    }
}

__global__ __launch_bounds__(256) void dinv_kernel(const int* __restrict__ deg,
                                                   float* __restrict__ dinv,
                                                   float* __restrict__ inv) {
    int i = blockIdx.x * blockDim.x + threadIdx.x;
    if (i < N_NODES_C) {
        float d = (float)(deg[i] + 1);   // +1 self-loop
        dinv[i] = rsqrtf(d);
        inv[i]  = 1.0f / d;
    }
}

// ---------- h = x @ W^T  (W in LDS, x tile in LDS) ----------
__global__ __launch_bounds__(256) void gemm_kernel(const float* __restrict__ x,
                                                   const float* __restrict__ W,
                                                   float* __restrict__ h) {
    __shared__ float Wl[DIM * 65];    // pad 65: bank = (c+k)%32, conflict-free
    __shared__ float xs[32][DIM];
    int t = threadIdx.x;
    for (int i = t; i < DIM * DIM; i += 256) {
        Wl[(i >> 6) * 65 + (i & 63)] = W[i];
    }
    int r0 = blockIdx.x * 32;
    for (int i = t; i < 32 * DIM; i += 256) {
        int row = i >> 6, col = i & 63;
        int r = r0 + row;
        xs[row][col] = (r < N_NODES_C) ? x[(size_t)r * DIM + col] : 0.0f;
    }
    __syncthreads();
    int wv = t >> 6, c = t & 63;
    for (int it = 0; it < 8; ++it) {
        int rl = it * 4 + wv;
        int r = r0 + rl;
        float acc = 0.0f;
#pragma unroll
        for (int k = 0; k < DIM; ++k) acc += xs[rl][k] * Wl[c * 65 + k];
        if (r < N_NODES_C) h[(size_t)r * DIM + c] = acc;
    }
}

// ---------- edge aggregation: wave per edge, lane = channel ----------
__global__ __launch_bounds__(256) void agg_kernel(const void* __restrict__ ei,
                                                  const int* __restrict__ flag,
                                                  const float* __restrict__ h,
                                                  const float* __restrict__ dinv,
                                                  float* __restrict__ out) {
    int is64 = *flag;
    int lane = threadIdx.x & 63;
    int wid = blockIdx.x * (blockDim.x >> 6) + (threadIdx.x >> 6);
    int nw = gridDim.x * (blockDim.x >> 6);
    for (int e = wid; e < N_EDGES_C; e += nw) {
        int s  = ld_idx(ei, is64, (size_t)e);
        int tg = ld_idx(ei, is64, (size_t)N_EDGES_C + e);
        float nrm = dinv[s] * dinv[tg];
        float v = h[(size_t)s * DIM + lane] * nrm;
        unsafeAtomicAdd(&out[(size_t)tg * DIM + lane], v);
    }
}

// ---------- out = agg + h/deg + b (in place) + per-channel sum/sumsq ----------
__global__ __launch_bounds__(256) void finish_stats_kernel(const float* __restrict__ h,
                                                           const float* __restrict__ inv,
                                                           const float* __restrict__ b,
                                                           float* __restrict__ out,
                                                           float* __restrict__ sums,
                                                           float* __restrict__ sumsq) {
    int c = threadIdx.x & 63;
    int sub = threadIdx.x >> 6;   // 0..3
    float bc = b[c];
    float ls = 0.0f, lq = 0.0f;
    for (int r = blockIdx.x * 4 + sub; r < N_NODES_C; r += gridDim.x * 4) {
        size_t i = (size_t)r * DIM + c;
        float v = out[i] + h[i] * inv[r] + bc;
        out[i] = v;
        ls += v;
        lq += v * v;
    }
    __shared__ float ssum[256], ssq[256];
    ssum[threadIdx.x] = ls;
    ssq[threadIdx.x] = lq;
    __syncthreads();
    if (sub == 0) {
        float a = ls + ssum[64 + c] + ssum[128 + c] + ssum[192 + c];
        float q = lq + ssq[64 + c] + ssq[128 + c] + ssq[192 + c];
        unsafeAtomicAdd(&sums[c], a);
        unsafeAtomicAdd(&sumsq[c], q);
    }
}

__global__ void bnparam_kernel(const float* __restrict__ sums,
                               const float* __restrict__ sumsq,
                               const float* __restrict__ gamma,
                               const float* __restrict__ beta,
                               float* __restrict__ scale,
                               float* __restrict__ shift) {
    int c = threadIdx.x;
    if (c < DIM) {
        float m = sums[c] * (1.0f / N_NODES_C);
        float var = sumsq[c] * (1.0f / N_NODES_C) - m * m;
        float sc = gamma[c] * rsqrtf(var + BN_EPS_C);
        scale[c] = sc;
        shift[c] = beta[c] - m * sc;
    }
}

__global__ __launch_bounds__(256) void bnrelu_kernel(float4* __restrict__ out,
                                                     const float* __restrict__ scale,
                                                     const float* __restrict__ shift) {
    const int n4 = N_NODES_C * (DIM / 4);
    int stride = gridDim.x * blockDim.x;
    for (int i = blockIdx.x * blockDim.x + threadIdx.x; i < n4; i += stride) {
        int cb = (i & 15) * 4;
        float4 v = out[i];
        v.x = fmaxf(fmaf(v.x, scale[cb + 0], shift[cb + 0]), 0.0f);
        v.y = fmaxf(fmaf(v.y, scale[cb + 1], shift[cb + 1]), 0.0f);
        v.z = fmaxf(fmaf(v.z, scale[cb + 2], shift[cb + 2]), 0.0f);
        v.w = fmaxf(fmaf(v.w, scale[cb + 3], shift[cb + 3]), 0.0f);
        out[i] = v;
    }
}

extern "C" void kernel_launch(void* const* d_in, const int* in_sizes, int n_in,
                              void* d_out, int out_size, void* d_ws, size_t ws_size,
                              hipStream_t stream) {
    const float* x     = (const float*)d_in[0];
    const void*  ei    = d_in[1];
    const float* W     = (const float*)d_in[2];
    const float* b     = (const float*)d_in[3];
    const float* gamma = (const float*)d_in[4];
    const float* beta  = (const float*)d_in[5];
    float* out = (float*)d_out;

    char* ws = (char*)d_ws;
    int*   flag  = (int*)(ws + 0);
    int*   deg   = (int*)(ws + 256);          // 400000 B
    float* dinv  = (float*)(ws + 400384);     // 400000 B
    float* inv   = (float*)(ws + 800512);     // 400000 B
    float* sums  = (float*)(ws + 1200640);    // 256 B
    float* sumsq = (float*)(ws + 1200896);    // 256 B
    float* scale = (float*)(ws + 1201152);    // 256 B
    float* shift = (float*)(ws + 1201408);    // 256 B
    float* h     = (float*)(ws + 1201664);    // 25,600,000 B

    // zero accumulators (harness poisons ws/out with 0xAA once)
    hipMemsetAsync(out, 0, (size_t)out_size * sizeof(float), stream);
    hipMemsetAsync(deg, 0, (size_t)N_NODES_C * sizeof(int), stream);
    hipMemsetAsync(sums, 0, 512, stream);  // sums + sumsq contiguous

    probe_kernel<<<1, 64, 0, stream>>>((const unsigned int*)ei, flag);
    deg_kernel<<<1024, 256, 0, stream>>>(ei, flag, deg);
    dinv_kernel<<<(N_NODES_C + 255) / 256, 256, 0, stream>>>(deg, dinv, inv);
    gemm_kernel<<<(N_NODES_C + 31) / 32, 256, 0, stream>>>(x, W, h);
    agg_kernel<<<2048, 256, 0, stream>>>(ei, flag, h, dinv, out);
    finish_stats_kernel<<<512, 256, 0, stream>>>(h, inv, b, out, sums, sumsq);
    bnparam_kernel<<<1, 64, 0, stream>>>(sums, sumsq, gamma, beta, scale, shift);
    bnrelu_kernel<<<1024, 256, 0, stream>>>((float4*)out, scale, shift);
}

// Round 2
// 390.269 us; speedup vs baseline: 1.3435x; 1.3435x over previous
//
#include <hip/hip_runtime.h>
#include <stdint.h>

#define N_NODES_C 100000
#define N_EDGES_C 1600000
#define DIM 64
#define BN_EPS_C 1e-5f

// ---------- index helper: supports int32 or int64 edge_index ----------
__device__ __forceinline__ int ld_idx(const void* p, int is64, size_t i) {
    if (is64) return (int)((const long long*)p)[i];
    return ((const int*)p)[i];
}

// Probe: if edge_index is int64, the high 32-bit word of every element is 0
// (values are in [0, 100000)). Check odd words of the first 32 elements.
__global__ void probe_kernel(const unsigned int* __restrict__ p, int* __restrict__ flag) {
    if (threadIdx.x == 0 && blockIdx.x == 0) {
        int is64 = 1;
        for (int i = 1; i < 64; i += 2) {
            if (p[i] != 0u) { is64 = 0; break; }
        }
        *flag = is64;
    }
}

// ---------- degree count (in-degree at tgt) ----------
__global__ __launch_bounds__(256) void deg_kernel(const void* __restrict__ ei,
                                                  const int* __restrict__ flag,
                                                  int* __restrict__ deg) {
    int is64 = *flag;
    int stride = gridDim.x * blockDim.x;
    for (int e = blockIdx.x * blockDim.x + threadIdx.x; e < N_EDGES_C; e += stride) {
        int t = ld_idx(ei, is64, (size_t)N_EDGES_C + e);
        atomicAdd(&deg[t], 1);
    }
}

// ---------- rowbase assignment (wave scan + cursor atomic) + dinv/inv ----------
__global__ __launch_bounds__(256) void scan_kernel(const int* __restrict__ deg,
                                                   int* __restrict__ cursor,
                                                   int* __restrict__ rowbase,
                                                   int* __restrict__ cursor2,
                                                   float* __restrict__ dinv,
                                                   float* __restrict__ inv) {
    int i = blockIdx.x * blockDim.x + threadIdx.x;
    int lane = threadIdx.x & 63;
    int v = (i < N_NODES_C) ? deg[i] : 0;
    int incl = v;
#pragma unroll
    for (int off = 1; off < 64; off <<= 1) {
        int u = __shfl_up(incl, off, 64);
        if (lane >= off) incl += u;
    }
    int excl = incl - v;
    int base = 0;
    if (lane == 63) base = atomicAdd(cursor, incl);
    base = __shfl(base, 63, 64);
    if (i < N_NODES_C) {
        int rb = base + excl;
        rowbase[i] = rb;
        cursor2[i] = rb;
        float d = (float)(deg[i] + 1);   // +1 self-loop
        dinv[i] = rsqrtf(d);
        inv[i]  = 1.0f / d;
    }
}

// ---------- scatter edges into CSR order by target ----------
__global__ __launch_bounds__(256) void scatter_kernel(const void* __restrict__ ei,
                                                      const int* __restrict__ flag,
                                                      int* __restrict__ cursor2,
                                                      int* __restrict__ csr) {
    int is64 = *flag;
    int stride = gridDim.x * blockDim.x;
    for (int e = blockIdx.x * blockDim.x + threadIdx.x; e < N_EDGES_C; e += stride) {
        int s  = ld_idx(ei, is64, (size_t)e);
        int tg = ld_idx(ei, is64, (size_t)N_EDGES_C + e);
        int pos = atomicAdd(&cursor2[tg], 1);
        csr[pos] = s;
    }
}

// ---------- h = x @ W^T  (W in LDS, x tile in LDS) ----------
__global__ __launch_bounds__(256) void gemm_kernel(const float* __restrict__ x,
                                                   const float* __restrict__ W,
                                                   float* __restrict__ h) {
    __shared__ float Wl[DIM * 65];
    __shared__ float xs[32][DIM];
    int t = threadIdx.x;
    for (int i = t; i < DIM * DIM; i += 256) {
        Wl[(i >> 6) * 65 + (i & 63)] = W[i];
    }
    int r0 = blockIdx.x * 32;
    for (int i = t; i < 32 * DIM; i += 256) {
        int row = i >> 6, col = i & 63;
        int r = r0 + row;
        xs[row][col] = (r < N_NODES_C) ? x[(size_t)r * DIM + col] : 0.0f;
    }
    __syncthreads();
    int wv = t >> 6, c = t & 63;
    for (int it = 0; it < 8; ++it) {
        int rl = it * 4 + wv;
        int r = r0 + rl;
        float acc = 0.0f;
#pragma unroll
        for (int k = 0; k < DIM; ++k) acc += xs[rl][k] * Wl[c * 65 + k];
        if (r < N_NODES_C) h[(size_t)r * DIM + c] = acc;
    }
}

// ---------- gather: one wave per node; fold self-loop + bias + BN stats ----------
__global__ __launch_bounds__(256) void gather_kernel(const int* __restrict__ csr,
                                                     const int* __restrict__ rowbase,
                                                     const int* __restrict__ deg,
                                                     const float* __restrict__ dinv,
                                                     const float* __restrict__ inv,
                                                     const float* __restrict__ h,
                                                     const float* __restrict__ b,
                                                     float* __restrict__ out,
                                                     float* __restrict__ sums,
                                                     float* __restrict__ sumsq) {
    int lane = threadIdx.x & 63;
    int wid = blockIdx.x * (blockDim.x >> 6) + (threadIdx.x >> 6);
    int nw = gridDim.x * (blockDim.x >> 6);
    float bc = b[lane];
    float ls = 0.0f, lq = 0.0f;
    for (int t = wid; t < N_NODES_C; t += nw) {
        float dt = dinv[t];
        int base = rowbase[t];
        int n = deg[t];
        float acc = 0.0f;
        int j = 0;
        for (; j + 4 <= n; j += 4) {
            int s0 = csr[base + j + 0];
            int s1 = csr[base + j + 1];
            int s2 = csr[base + j + 2];
            int s3 = csr[base + j + 3];
            float w0 = dinv[s0] * dt;
            float w1 = dinv[s1] * dt;
            float w2 = dinv[s2] * dt;
            float w3 = dinv[s3] * dt;
            float h0 = h[(size_t)s0 * DIM + lane];
            float h1 = h[(size_t)s1 * DIM + lane];
            float h2 = h[(size_t)s2 * DIM + lane];
            float h3 = h[(size_t)s3 * DIM + lane];
            acc = fmaf(h0, w0, acc);
            acc = fmaf(h1, w1, acc);
            acc = fmaf(h2, w2, acc);
            acc = fmaf(h3, w3, acc);
        }
        for (; j < n; ++j) {
            int s = csr[base + j];
            acc = fmaf(h[(size_t)s * DIM + lane], dinv[s] * dt, acc);
        }
        float v = acc + h[(size_t)t * DIM + lane] * inv[t] + bc;
        out[(size_t)t * DIM + lane] = v;
        ls += v;
        lq += v * v;
    }
    __shared__ float ssum[256], ssq[256];
    ssum[threadIdx.x] = ls;
    ssq[threadIdx.x] = lq;
    __syncthreads();
    if (threadIdx.x < 64) {
        float a = ls + ssum[64 + lane] + ssum[128 + lane] + ssum[192 + lane];
        float q = lq + ssq[64 + lane] + ssq[128 + lane] + ssq[192 + lane];
        unsafeAtomicAdd(&sums[lane], a);
        unsafeAtomicAdd(&sumsq[lane], q);
    }
}

__global__ void bnparam_kernel(const float* __restrict__ sums,
                               const float* __restrict__ sumsq,
                               const float* __restrict__ gamma,
                               const float* __restrict__ beta,
                               float* __restrict__ scale,
                               float* __restrict__ shift) {
    int c = threadIdx.x;
    if (c < DIM) {
        float m = sums[c] * (1.0f / N_NODES_C);
        float var = sumsq[c] * (1.0f / N_NODES_C) - m * m;
        float sc = gamma[c] * rsqrtf(var + BN_EPS_C);
        scale[c] = sc;
        shift[c] = beta[c] - m * sc;
    }
}

__global__ __launch_bounds__(256) void bnrelu_kernel(float4* __restrict__ out,
                                                     const float* __restrict__ scale,
                                                     const float* __restrict__ shift) {
    const int n4 = N_NODES_C * (DIM / 4);
    int stride = gridDim.x * blockDim.x;
    for (int i = blockIdx.x * blockDim.x + threadIdx.x; i < n4; i += stride) {
        int cb = (i & 15) * 4;
        float4 v = out[i];
        v.x = fmaxf(fmaf(v.x, scale[cb + 0], shift[cb + 0]), 0.0f);
        v.y = fmaxf(fmaf(v.y, scale[cb + 1], shift[cb + 1]), 0.0f);
        v.z = fmaxf(fmaf(v.z, scale[cb + 2], shift[cb + 2]), 0.0f);
        v.w = fmaxf(fmaf(v.w, scale[cb + 3], shift[cb + 3]), 0.0f);
        out[i] = v;
    }
}

extern "C" void kernel_launch(void* const* d_in, const int* in_sizes, int n_in,
                              void* d_out, int out_size, void* d_ws, size_t ws_size,
                              hipStream_t stream) {
    const float* x     = (const float*)d_in[0];
    const void*  ei    = d_in[1];
    const float* W     = (const float*)d_in[2];
    const float* b     = (const float*)d_in[3];
    const float* gamma = (const float*)d_in[4];
    const float* beta  = (const float*)d_in[5];
    float* out = (float*)d_out;

    char* ws = (char*)d_ws;
    int*   flag    = (int*)(ws + 0);
    int*   cursor  = (int*)(ws + 64);
    int*   deg     = (int*)(ws + 256);       // 400000 B
    int*   rowbase = (int*)(ws + 400384);    // 400000 B
    int*   cursor2 = (int*)(ws + 800512);    // 400000 B
    float* dinv    = (float*)(ws + 1200640); // 400000 B
    float* inv     = (float*)(ws + 1600768); // 400000 B
    float* sums    = (float*)(ws + 2000896); // 256 B
    float* sumsq   = (float*)(ws + 2001152); // 256 B
    float* scale   = (float*)(ws + 2001408); // 256 B
    float* shift   = (float*)(ws + 2001664); // 256 B
    int*   csr     = (int*)(ws + 2001920);   // 6,400,000 B
    float* h       = (float*)(ws + 8401920); // 25,600,000 B

    hipMemsetAsync(deg, 0, (size_t)N_NODES_C * sizeof(int), stream);
    hipMemsetAsync(cursor, 0, sizeof(int), stream);
    hipMemsetAsync(sums, 0, 512, stream);  // sums + sumsq contiguous

    probe_kernel<<<1, 64, 0, stream>>>((const unsigned int*)ei, flag);
    gemm_kernel<<<(N_NODES_C + 31) / 32, 256, 0, stream>>>(x, W, h);
    deg_kernel<<<1024, 256, 0, stream>>>(ei, flag, deg);
    scan_kernel<<<(N_NODES_C + 255) / 256, 256, 0, stream>>>(deg, cursor, rowbase,
                                                             cursor2, dinv, inv);
    scatter_kernel<<<2048, 256, 0, stream>>>(ei, flag, cursor2, csr);
    gather_kernel<<<2048, 256, 0, stream>>>(csr, rowbase, deg, dinv, inv, h, b,
                                            out, sums, sumsq);
    bnparam_kernel<<<1, 64, 0, stream>>>(sums, sumsq, gamma, beta, scale, shift);
    bnrelu_kernel<<<1024, 256, 0, stream>>>((float4*)out, scale, shift);
}